// Round 3
// baseline (106.062 us; speedup 1.0000x reference)
//
#include <hip/hip_runtime.h>

// All-pairs edge MLP, N_E=1024, NIN=64, HID=128, OUT=64, fp32.
// out[i] = ((1/1023) * sum_{k!=i} tanh(A[i]+B[k])) @ W2 + b2
//   A = x@W1[:64,:],  B = x@W1[64:,:] + b1
// Rank-separated tanh via 2D Chebyshev (P=30 terms, domain [-5.5,5.5]^2):
//   sum_k tanh(a_i+b_k) = sum_p T_p(a_i) V_p[h],  V = C @ M,
//   M_q[h] = sum_k T_q(b_k[h]).
// R3: 2 kernels total.
//   K1: block 0 computes C (fp32 DCT-I, NQ=32 Lobatto, cos-recurrence,
//       conflict-free padded LDS); blocks 1..16 each recompute B for 64 rows
//       (W1 column in VGPRs, x via wave-uniform s_load) and write Chebyshev
//       moment partials Mpart[16][30][128] (no atomics, no zero-init dep).
//   K2: 256 blocks x 256 thr, 4 rows each: reduce Mpart -> regs, V=C@M with
//       scalar-loaded C, recompute A/B per row, Chebyshev dot + exact
//       exp2-tanh self-term, fused W2 matvec epilogue (float4 LDS reads).
// Exact-vs-approx self term mismatch ~2e-4; all errors << bf16 floor.

#define N_E   1024
#define NIN   64
#define HID   128
#define OUTD  64
#define PCH   30      // Chebyshev terms per variable
#define NQ    32      // DCT-I grid: NQ+1 Lobatto points
#define NPART 16      // moment partials (64 rows each)
#define S_CH  5.5f

static constexpr float INV_S     = 1.0f / 5.5f;
static constexpr float TWO_LOG2E = 2.8853900817779268f; // 2*log2(e)
static constexpr float PI_F      = 3.14159265358979323846f;

__device__ __forceinline__ float tanh_fast(float u) {
  // tanh(u) = 1 - 2/(1+exp2(u*2log2e))
  return 1.0f - 2.0f * __builtin_amdgcn_rcpf(
      1.0f + __builtin_amdgcn_exp2f(u * TWO_LOG2E));
}

// ---- K1: coefficients + moment partials -------------------------------
__global__ __launch_bounds__(256, 1) void k1_coeff_moments(
    const float* __restrict__ x, const float* __restrict__ W1,
    const float* __restrict__ b1,
    float* __restrict__ C, float* __restrict__ Mpart) {
  const int t = threadIdx.x;
  if (blockIdx.x == 0) {
    // ---- Chebyshev coefficient matrix C[p][q], fp32 DCT-I ----
    __shared__ float ctab[NQ + 1];
    __shared__ float fg[(NQ + 1) * (NQ + 2)];  // [j][l], row stride 34 (odd*2 -> 2-way max)
    __shared__ float G[PCH * (NQ + 2)];        // [q][j], row stride 34
    if (t <= NQ) ctab[t] = cosf((float)t * (PI_F / (float)NQ));
    __syncthreads();
    for (int idx = t; idx < (NQ + 1) * (NQ + 1); idx += 256) {
      const int j = idx / (NQ + 1), l = idx % (NQ + 1);
      fg[j * (NQ + 2) + l] = tanh_fast(S_CH * (ctab[j] + ctab[l]));
    }
    __syncthreads();
    // G[q][j] = sum_l w_l fg[j][l] cos(q l pi/NQ)  (cos via recurrence)
    for (int idx = t; idx < PCH * (NQ + 1); idx += 256) {
      const int q = idx / (NQ + 1), j = idx % (NQ + 1);
      const float cphi = ctab[q];
      float c0 = 1.f, c1 = cphi;
      float s = 0.5f * fg[j * (NQ + 2) + 0];   // l=0: w=1/2, cos=1
      for (int l = 1; l <= NQ; ++l) {
        const float w = (l == NQ) ? 0.5f : 1.0f;
        s += w * fg[j * (NQ + 2) + l] * c1;
        const float c2 = 2.f * cphi * c1 - c0; c0 = c1; c1 = c2;
      }
      G[q * (NQ + 2) + j] = s;
    }
    __syncthreads();
    // C[p][q] = cp cq sum_j w_j G[q][j] cos(p j pi/NQ)
    for (int idx = t; idx < PCH * PCH; idx += 256) {
      const int p = idx / PCH, q = idx % PCH;
      const float cphi = ctab[p];
      float c0 = 1.f, c1 = cphi;
      float s = 0.5f * G[q * (NQ + 2) + 0];
      for (int j = 1; j <= NQ; ++j) {
        const float w = (j == NQ) ? 0.5f : 1.0f;
        s += w * G[q * (NQ + 2) + j] * c1;
        const float c2 = 2.f * cphi * c1 - c0; c0 = c1; c1 = c2;
      }
      const float cp = (p == 0 ? 1.f : 2.f) / (float)NQ;
      const float cq = (q == 0 ? 1.f : 2.f) / (float)NQ;
      C[p * PCH + q] = s * cp * cq;
    }
  } else {
    // ---- moment partial: rows k in [part*64, part*64+64) ----
    const int part = blockIdx.x - 1;
    const int h = t & (HID - 1), half = t >> 7;   // half is wave-uniform
    float w1c[NIN];
    #pragma unroll
    for (int f = 0; f < NIN; ++f) w1c[f] = W1[(NIN + f) * HID + h];  // coalesced over h
    const float b1h = b1[h];
    float acc[PCH];
    #pragma unroll
    for (int q = 0; q < PCH; ++q) acc[q] = 0.f;
    const int k0 = part * 64 + half * 32;
    for (int kk = 0; kk < 32; ++kk) {
      const float* __restrict__ xr = x + (k0 + kk) * NIN;  // wave-uniform -> s_load
      float b = b1h;
      #pragma unroll
      for (int f = 0; f < NIN; ++f) b += xr[f] * w1c[f];
      const float u = fminf(fmaxf(b, -S_CH), S_CH) * INV_S;
      acc[0] += 1.f;
      acc[1] += u;
      float t0 = 1.f, t1 = u;
      const float u2 = u + u;
      #pragma unroll
      for (int q = 2; q < PCH; ++q) {
        const float t2 = u2 * t1 - t0;
        acc[q] += t2;
        t0 = t1; t1 = t2;
      }
    }
    __shared__ float Msub[PCH][256];  // 30 KB
    #pragma unroll
    for (int q = 0; q < PCH; ++q) Msub[q][t] = acc[q];
    __syncthreads();
    float* __restrict__ Mp = Mpart + part * PCH * HID;
    for (int idx = t; idx < PCH * HID; idx += 256) {
      const int q = idx >> 7, hh = idx & (HID - 1);
      Mp[idx] = Msub[q][hh] + Msub[q][hh + HID];
    }
  }
}

// ---- K2: fused reduce + V + A/B recompute + combine + W2 epilogue -----
__global__ __launch_bounds__(256, 1) void k2_combine_out(
    const float* __restrict__ x, const float* __restrict__ W1,
    const float* __restrict__ b1, const float* __restrict__ W2,
    const float* __restrict__ b2, const float* __restrict__ C,
    const float* __restrict__ Mpart, float* __restrict__ out) {
  const int t = threadIdx.x;
  const int h = t & (HID - 1), sub = t >> 7;   // sub wave-uniform
  __shared__ float Vs[2][PCH][HID];            // 30 KB
  __shared__ float Sl[4][HID];                 // 2 KB, 16B-aligned rows

  // phase 1: reduce Mpart over parts for q in [sub*15, sub*15+15)
  float m[PCH / 2];
  #pragma unroll
  for (int qq = 0; qq < PCH / 2; ++qq) {
    const int q = sub * (PCH / 2) + qq;
    float s = 0.f;
    #pragma unroll
    for (int part = 0; part < NPART; ++part)
      s += Mpart[part * PCH * HID + q * HID + h];   // coalesced over h
    m[qq] = s;
  }
  // phase 2: partial V[p][h] from this sub's q-range; C is wave-uniform -> s_load
  #pragma unroll
  for (int p = 0; p < PCH; ++p) {
    float s = 0.f;
    #pragma unroll
    for (int qq = 0; qq < PCH / 2; ++qq)
      s += C[p * PCH + sub * (PCH / 2) + qq] * m[qq];
    Vs[sub][p][h] = s;
  }
  __syncthreads();
  float v[PCH];
  #pragma unroll
  for (int p = 0; p < PCH; ++p) v[p] = Vs[0][p][h] + Vs[1][p][h];

  // phase 3: rows i0 = blockIdx*4 + sub*2 + {0,1}; recompute A,B
  const int i0 = blockIdx.x * 4 + sub * 2;     // wave-uniform
  const float* __restrict__ x0 = x + i0 * NIN;       // s_load
  const float* __restrict__ x1 = x + (i0 + 1) * NIN; // s_load
  float w1c[NIN];
  #pragma unroll
  for (int f = 0; f < NIN; ++f) w1c[f] = W1[f * HID + h];
  float a0 = 0.f, a1 = 0.f;
  #pragma unroll
  for (int f = 0; f < NIN; ++f) {
    a0 += x0[f] * w1c[f];
    a1 += x1[f] * w1c[f];
  }
  #pragma unroll
  for (int f = 0; f < NIN; ++f) w1c[f] = W1[(NIN + f) * HID + h];
  const float b1h = b1[h];
  float bb0 = b1h, bb1 = b1h;
  #pragma unroll
  for (int f = 0; f < NIN; ++f) {
    bb0 += x0[f] * w1c[f];
    bb1 += x1[f] * w1c[f];
  }
  #pragma unroll
  for (int r = 0; r < 2; ++r) {
    const float ar = r ? a1 : a0;
    const float br = r ? bb1 : bb0;
    const float ua = fminf(fmaxf(ar, -S_CH), S_CH) * INV_S;
    float s = v[0] + ua * v[1];
    float t0 = 1.f, t1 = ua;
    const float ua2 = ua + ua;
    #pragma unroll
    for (int p = 2; p < PCH; ++p) {
      const float t2 = ua2 * t1 - t0;
      s += t2 * v[p];
      t0 = t1; t1 = t2;
    }
    const float self = tanh_fast(ar + br);  // exact k==i term
    Sl[sub * 2 + r][h] = (s - self) * (1.0f / (float)(N_E - 1));
  }
  __syncthreads();
  // phase 4: out[i][o] = b2[o] + Sl[r] @ W2
  const int o = t & (OUTD - 1), r4 = t >> 6;   // r4 wave-uniform
  const float4* __restrict__ slr = (const float4*)&Sl[r4][0];
  float accO = b2[o];
  #pragma unroll
  for (int hh4 = 0; hh4 < HID / 4; ++hh4) {
    const float4 sv = slr[hh4];               // LDS b128 broadcast
    const int hb = hh4 * 4;
    accO += sv.x * W2[(hb + 0) * OUTD + o];
    accO += sv.y * W2[(hb + 1) * OUTD + o];
    accO += sv.z * W2[(hb + 2) * OUTD + o];
    accO += sv.w * W2[(hb + 3) * OUTD + o];
  }
  out[(blockIdx.x * 4 + r4) * OUTD + o] = accO;
}

extern "C" void kernel_launch(void* const* d_in, const int* in_sizes, int n_in,
                              void* d_out, int out_size, void* d_ws, size_t ws_size,
                              hipStream_t stream) {
  const float* x  = (const float*)d_in[0];
  const float* W1 = (const float*)d_in[1];
  const float* b1 = (const float*)d_in[2];
  const float* W2 = (const float*)d_in[3];
  const float* b2 = (const float*)d_in[4];
  float* out = (float*)d_out;

  float* C     = (float*)d_ws;              // [PCH][PCH]
  float* Mpart = C + PCH * PCH;             // [NPART][PCH][HID]

  k1_coeff_moments<<<1 + NPART, 256, 0, stream>>>(x, W1, b1, C, Mpart);
  k2_combine_out<<<N_E / 4, 256, 0, stream>>>(x, W1, b1, W2, b2, C, Mpart, out);
}

// Round 4
// 76.352 us; speedup vs baseline: 1.3891x; 1.3891x over previous
//
#include <hip/hip_runtime.h>

// All-pairs edge MLP, N_E=1024, NIN=64, HID=128, OUT=64, fp32.
// out[i] = ((1/1023) * sum_{k!=i} tanh(A[i]+B[k])) @ W2 + b2
//   A = x@W1[:64,:],  B = x@W1[64:,:] + b1
// Rank-separated tanh via 2D Chebyshev (P=30, domain [-5.5,5.5]^2):
//   sum_k tanh(a_i+b_k) = sum_p T_p(a_i) V_p[h],  V = C @ M,
//   M_q[h] = sum_k T_q(b_k[h]).
// R4 = R2 structure (proven fast paths) + R3's fp32 coefficient block
// (proven accurate) replacing the slow fp64 one. No register-array
// recompute tricks (R3's spill lesson: moments must read B, not rebuild it).

#define N_E  1024
#define NIN  64
#define HID  128
#define OUTD 64
#define PCH  30      // Chebyshev terms per variable
#define NQ   32      // DCT-I grid: NQ+1 Lobatto points
#define S_CH 5.5f

static constexpr float INV_S     = 1.0f / 5.5f;
static constexpr float TWO_LOG2E = 2.8853900817779268f; // 2*log2(e)
static constexpr float PI_F      = 3.14159265358979323846f;

__device__ __forceinline__ float tanh_fast(float u) {
  // tanh(u) = 1 - 2/(1+exp2(u*2log2e))
  return 1.0f - 2.0f * __builtin_amdgcn_rcpf(
      1.0f + __builtin_amdgcn_exp2f(u * TWO_LOG2E));
}

// ---- K1: blocks 0..511 compute A,B (2 rows each); block 512 computes the
// PCH x PCH Chebyshev coefficient matrix C in fp32 and zeroes M.
__global__ __launch_bounds__(256) void prep_coeff_kernel(
    const float* __restrict__ x, const float* __restrict__ W1,
    const float* __restrict__ b1,
    float* __restrict__ A, float* __restrict__ B,
    float* __restrict__ C, float* __restrict__ M) {
  const int t = threadIdx.x;
  if (blockIdx.x < N_E / 2) {
    __shared__ float xs[2][NIN];
    const int sub = t >> 7, h = t & (HID - 1);
    const int i = blockIdx.x * 2 + sub;
    if (t < 2 * NIN) xs[t >> 6][t & 63] = x[(blockIdx.x * 2 + (t >> 6)) * NIN + (t & 63)];
    __syncthreads();
    float accA = 0.f, accB = 0.f;
    #pragma unroll 8
    for (int f = 0; f < NIN; ++f) {
      const float xv = xs[sub][f];
      accA += xv * W1[f * HID + h];             // coalesced over h
      accB += xv * W1[(NIN + f) * HID + h];
    }
    A[i * HID + h] = accA;
    B[i * HID + h] = accB + b1[h];
  } else {
    // ---- fp32 Chebyshev coefficient matrix C[p][q] via DCT-I ----
    __shared__ float ctab[NQ + 1];
    __shared__ float fg[(NQ + 1) * (NQ + 2)];  // [j][l], padded row stride
    __shared__ float G[PCH * (NQ + 2)];        // [q][j], padded row stride
    if (t <= NQ) ctab[t] = cosf((float)t * (PI_F / (float)NQ));
    for (int idx = t; idx < PCH * HID; idx += 256) M[idx] = 0.f;  // zero moments
    __syncthreads();
    for (int idx = t; idx < (NQ + 1) * (NQ + 1); idx += 256) {
      const int j = idx / (NQ + 1), l = idx % (NQ + 1);
      fg[j * (NQ + 2) + l] = tanh_fast(S_CH * (ctab[j] + ctab[l]));
    }
    __syncthreads();
    // G[q][j] = sum_l w_l fg[j][l] cos(q l pi/NQ)  (cos via recurrence)
    for (int idx = t; idx < PCH * (NQ + 1); idx += 256) {
      const int q = idx / (NQ + 1), j = idx % (NQ + 1);
      const float cphi = ctab[q];
      float c0 = 1.f, c1 = cphi;
      float s = 0.5f * fg[j * (NQ + 2) + 0];   // l=0: w=1/2, cos=1
      for (int l = 1; l <= NQ; ++l) {
        const float w = (l == NQ) ? 0.5f : 1.0f;
        s += w * fg[j * (NQ + 2) + l] * c1;
        const float c2 = 2.f * cphi * c1 - c0; c0 = c1; c1 = c2;
      }
      G[q * (NQ + 2) + j] = s;
    }
    __syncthreads();
    // C[p][q] = cp cq sum_j w_j G[q][j] cos(p j pi/NQ)
    for (int idx = t; idx < PCH * PCH; idx += 256) {
      const int p = idx / PCH, q = idx % PCH;
      const float cphi = ctab[p];
      float c0 = 1.f, c1 = cphi;
      float s = 0.5f * G[q * (NQ + 2) + 0];
      for (int j = 1; j <= NQ; ++j) {
        const float w = (j == NQ) ? 0.5f : 1.0f;
        s += w * G[q * (NQ + 2) + j] * c1;
        const float c2 = 2.f * cphi * c1 - c0; c0 = c1; c1 = c2;
      }
      const float cp = (p == 0 ? 1.f : 2.f) / (float)NQ;
      const float cq = (q == 0 ? 1.f : 2.f) / (float)NQ;
      C[p * PCH + q] = s * cp * cq;
    }
  }
}

// ---- K2: M_q[h] += sum_k T_q(clamp(B[k,h])/s). 64 blocks x 16 k each.
__global__ __launch_bounds__(256) void moments_kernel(
    const float* __restrict__ B, float* __restrict__ M) {
  __shared__ float Msub[PCH][256];
  const int t = threadIdx.x;
  const int h = t & (HID - 1), sub = t >> 7;
  float acc[PCH];
  #pragma unroll
  for (int q = 0; q < PCH; ++q) acc[q] = 0.f;
  const int k0 = blockIdx.x * 16 + sub * 8;
  for (int j = 0; j < 8; ++j) {
    float b = B[(k0 + j) * HID + h];              // coalesced over h
    b = fminf(fmaxf(b, -S_CH), S_CH) * INV_S;
    float t0 = 1.f, t1 = b;
    const float b2x = b + b;
    acc[0] += 1.f;
    acc[1] += b;
    #pragma unroll
    for (int q = 2; q < PCH; ++q) {
      const float t2 = b2x * t1 - t0;
      acc[q] += t2;
      t0 = t1; t1 = t2;
    }
  }
  #pragma unroll
  for (int q = 0; q < PCH; ++q) Msub[q][t] = acc[q];
  __syncthreads();
  for (int idx = t; idx < PCH * HID; idx += 256) {
    const int q = idx / HID, hh = idx % HID;
    atomicAdd(&M[q * HID + hh], Msub[q][hh] + Msub[q][hh + HID]);
  }
}

// ---- K3: V = C @ M  (PCH x HID)
__global__ __launch_bounds__(HID) void v_kernel(
    const float* __restrict__ C, const float* __restrict__ M,
    float* __restrict__ V) {
  const int p = blockIdx.x, h = threadIdx.x;
  float acc = 0.f;
  #pragma unroll
  for (int q = 0; q < PCH; ++q) acc += C[p * PCH + q] * M[q * HID + h];
  V[p * HID + h] = acc;
}

// ---- K4: S[i,h] = (sum_p T_p(a_i) V_p[h] - tanh(A+B)) / 1023,
// then fused out[i,:] = S[i,:] @ W2 + b2.
__global__ __launch_bounds__(HID) void combine_out_kernel(
    const float* __restrict__ A, const float* __restrict__ B,
    const float* __restrict__ V, const float* __restrict__ W2,
    const float* __restrict__ b2, float* __restrict__ out) {
  __shared__ float Sl[HID];
  __shared__ float red[2][OUTD];
  const int i = blockIdx.x, h = threadIdx.x;
  const float ar = A[i * HID + h], br = B[i * HID + h];
  const float a = fminf(fmaxf(ar, -S_CH), S_CH) * INV_S;
  float t0 = 1.f, t1 = a;
  const float a2x = a + a;
  float acc = V[h] + a * V[HID + h];
  #pragma unroll
  for (int p = 2; p < PCH; ++p) {
    const float t2 = a2x * t1 - t0;
    acc += t2 * V[p * HID + h];
    t0 = t1; t1 = t2;
  }
  const float ts = tanh_fast(ar + br);   // exact self term (k==i)
  Sl[h] = (acc - ts) * (1.f / (float)(N_E - 1));
  __syncthreads();
  const int o = h & (OUTD - 1), half = h >> 6;
  const int h0 = half * 64;
  float po = 0.f;
  #pragma unroll 16
  for (int hh = 0; hh < 64; ++hh)
    po += Sl[h0 + hh] * W2[(h0 + hh) * OUTD + o];   // coalesced over o
  red[half][o] = po;
  __syncthreads();
  if (h < OUTD) out[i * OUTD + h] = red[0][h] + red[1][h] + b2[h];
}

extern "C" void kernel_launch(void* const* d_in, const int* in_sizes, int n_in,
                              void* d_out, int out_size, void* d_ws, size_t ws_size,
                              hipStream_t stream) {
  const float* x  = (const float*)d_in[0];
  const float* W1 = (const float*)d_in[1];
  const float* b1 = (const float*)d_in[2];
  const float* W2 = (const float*)d_in[3];
  const float* b2 = (const float*)d_in[4];
  float* out = (float*)d_out;

  float* A = (float*)d_ws;             // [N_E][HID]
  float* B = A + N_E * HID;            // [N_E][HID]
  float* M = B + N_E * HID;            // [PCH][HID]
  float* V = M + PCH * HID;            // [PCH][HID]
  float* C = V + PCH * HID;            // [PCH][PCH]

  prep_coeff_kernel<<<N_E / 2 + 1, 256, 0, stream>>>(x, W1, b1, A, B, C, M);
  moments_kernel<<<N_E / 16, 256, 0, stream>>>(B, M);
  v_kernel<<<PCH, HID, 0, stream>>>(C, M, V);
  combine_out_kernel<<<N_E, HID, 0, stream>>>(A, B, V, W2, b2, out);
}